// Round 1
// baseline (580.931 us; speedup 1.0000x reference)
//
#include <hip/hip_runtime.h>
#include <stdint.h>

// GCN pipeline on MI355X:
//   h = emb[x]; 2x { msg = relu(h@W^T+b); h = (m/deg)@msg }; segment_max; linear.
// Factorization: (m/deg)@msg = diag(rsqrt(rd)) * m_bf16 @ (diag(rsqrt(cd))*msg)
// Kernels:
//   k_zero      : zero rd/cd accumulators
//   k_deg_cast  : read m fp32 (256MB), rd/cd sums, write m bf16 (128MB)
//   k_msg       : msgT[n][j] = bf16( relu(h[j]@W[n]+b[n]) * rsqrt(cd[j]) )  (MFMA)
//   k_gemm      : split-K=8 bf16 MFMA GEMM  part[kp] += m_bf16 @ msgT^T  (m97 structure)
//   k_pool      : sum partials, *rsqrt(rd), segment max (128 rows/graph), classifier

#define NN 8192
#define DH 128
#define NCLS 16
#define NGRAPH 64
#define SPLITK 8
#define KCHUNK (NN / SPLITK) // 1024

typedef float floatx4 __attribute__((ext_vector_type(4)));
typedef __bf16 bf16x8 __attribute__((ext_vector_type(8)));

__device__ __forceinline__ unsigned short f2bf_bits(float f) {
    union { float f; unsigned u; } v; v.f = f;
    unsigned u = v.u;
    u += 0x7fffu + ((u >> 16) & 1u);   // RNE
    return (unsigned short)(u >> 16);
}

__device__ __forceinline__ void gload16(const void* g, void* l) {
    __builtin_amdgcn_global_load_lds(
        (const __attribute__((address_space(1))) void*)g,
        (__attribute__((address_space(3))) void*)l, 16, 0, 0);
}

__global__ __launch_bounds__(256) void k_zero(float* p, int n) {
    int i = blockIdx.x * 256 + threadIdx.x;
    if (i < n) p[i] = 0.f;
}

// grid 1024 = 256 row-blocks (32 rows) x 4 col-blocks (2048 cols). 8 cols/thread.
__global__ __launch_bounds__(256) void k_deg_cast(
    const float* __restrict__ m, unsigned short* __restrict__ mb,
    float* __restrict__ rd, float* __restrict__ cd)
{
    int rb = blockIdx.x >> 2;
    int cb = blockIdx.x & 3;
    int tid = threadIdx.x;
    int lane = tid & 63;
    int c = cb * 2048 + tid * 8;
    int r0 = rb * 32;
    float cs[8];
#pragma unroll
    for (int u = 0; u < 8; ++u) cs[u] = 0.f;
#pragma unroll 2
    for (int r = 0; r < 32; ++r) {
        int row = r0 + r;
        const float* p = m + (size_t)row * NN + c;
        float4 a = *(const float4*)p;
        float4 b = *(const float4*)(p + 4);
        cs[0] += a.x; cs[1] += a.y; cs[2] += a.z; cs[3] += a.w;
        cs[4] += b.x; cs[5] += b.y; cs[6] += b.z; cs[7] += b.w;
        float rs = ((a.x + a.y) + (a.z + a.w)) + ((b.x + b.y) + (b.z + b.w));
#pragma unroll
        for (int off = 1; off < 64; off <<= 1) rs += __shfl_xor(rs, off, 64);
        if (lane == 0) atomicAdd(&rd[row], rs);
        uint4 o;
        o.x = (unsigned)f2bf_bits(a.x) | ((unsigned)f2bf_bits(a.y) << 16);
        o.y = (unsigned)f2bf_bits(a.z) | ((unsigned)f2bf_bits(a.w) << 16);
        o.z = (unsigned)f2bf_bits(b.x) | ((unsigned)f2bf_bits(b.y) << 16);
        o.w = (unsigned)f2bf_bits(b.z) | ((unsigned)f2bf_bits(b.w) << 16);
        *(uint4*)(mb + (size_t)row * NN + c) = o;
    }
#pragma unroll
    for (int u = 0; u < 8; ++u) atomicAdd(&cd[c + u], cs[u]);
}

// msgT[n][j] = bf16( relu( sum_e h[j][e]*w[n][e] + b[n] ) * rsqrt(cd[j]) )
// layer1: h[j] = emb[x[j]];  layer2: h[j] = rsqrt(rd[j]) * sum_p part[p][j][:]
// MFMA 16x16x32: A = w (M=n,K=e), B = h^T (K=e,N=j). D layout: col=lane&15(j), row=quad*4+reg(n).
// grid 128 blocks x 4 waves; wave handles 16 j, all 128 n.
__global__ __launch_bounds__(256) void k_msg(
    const int* __restrict__ x, const float* __restrict__ emb,
    const float* __restrict__ part, const float* __restrict__ rdv,
    const float* __restrict__ w, const float* __restrict__ bias,
    const float* __restrict__ cdv, unsigned short* __restrict__ msgT,
    int layer)
{
    int tid = threadIdx.x;
    int wv = tid >> 6, lane = tid & 63;
    int quad = lane >> 4, r16 = lane & 15;
    int j = blockIdx.x * 64 + wv * 16 + r16;

    floatx4 acc[8];
#pragma unroll
    for (int t = 0; t < 8; ++t) acc[t] = (floatx4)0.f;

    const float* src;
    float presc = 1.f;
    if (layer == 1) {
        src = emb + (size_t)x[j] * DH;
    } else {
        src = part + (size_t)j * DH;
        presc = rsqrtf(rdv[j]);
    }

#pragma unroll
    for (int e0 = 0; e0 < DH; e0 += 32) {
        int ke = e0 + quad * 8;
        float v[8];
        if (layer == 1) {
            float4 a = *(const float4*)(src + ke);
            float4 b = *(const float4*)(src + ke + 4);
            v[0] = a.x; v[1] = a.y; v[2] = a.z; v[3] = a.w;
            v[4] = b.x; v[5] = b.y; v[6] = b.z; v[7] = b.w;
        } else {
#pragma unroll
            for (int u = 0; u < 8; ++u) v[u] = 0.f;
#pragma unroll
            for (int p2 = 0; p2 < SPLITK; ++p2) {
                const float* pp = src + (size_t)p2 * ((size_t)NN * DH) + ke;
                float4 a = *(const float4*)pp;
                float4 b = *(const float4*)(pp + 4);
                v[0] += a.x; v[1] += a.y; v[2] += a.z; v[3] += a.w;
                v[4] += b.x; v[5] += b.y; v[6] += b.z; v[7] += b.w;
            }
#pragma unroll
            for (int u = 0; u < 8; ++u) v[u] *= presc;
        }
        bf16x8 bf;
#pragma unroll
        for (int u = 0; u < 8; ++u) bf[u] = (__bf16)v[u];
#pragma unroll
        for (int t = 0; t < 8; ++t) {
            const float* wp = w + (size_t)(t * 16 + r16) * DH + ke;
            float4 wa = *(const float4*)wp;
            float4 wb = *(const float4*)(wp + 4);
            bf16x8 af;
            af[0] = (__bf16)wa.x; af[1] = (__bf16)wa.y; af[2] = (__bf16)wa.z; af[3] = (__bf16)wa.w;
            af[4] = (__bf16)wb.x; af[5] = (__bf16)wb.y; af[6] = (__bf16)wb.z; af[7] = (__bf16)wb.w;
            acc[t] = __builtin_amdgcn_mfma_f32_16x16x32_bf16(af, bf, acc[t], 0, 0, 0);
        }
    }
    float cs = rsqrtf(cdv[j]);
#pragma unroll
    for (int t = 0; t < 8; ++t) {
#pragma unroll
        for (int r = 0; r < 4; ++r) {
            int n = t * 16 + quad * 4 + r;
            float val = acc[t][r] + bias[n];
            val = fmaxf(val, 0.f) * cs;
            msgT[(size_t)n * NN + j] = f2bf_bits(val);
        }
    }
}

// part[kp][i][n] = sum_{k in chunk kp} A[i][k] * Bt[n][k]
// m97 structure: BM=128, BN=128, BK=32, 4 waves of 64x64, global_load_lds width 16.
// grid = 64 m-blocks * SPLITK.
__global__ __launch_bounds__(256) void k_gemm(
    const unsigned short* __restrict__ A,   // 8192 x 8192 bf16 row-major
    const unsigned short* __restrict__ Bt,  // 128 x 8192 bf16 (N x K)
    float* __restrict__ part)               // SPLITK x 8192 x 128
{
    __shared__ unsigned short lA[128 * 32];
    __shared__ unsigned short lB[128 * 32];
    int mblk = blockIdx.x & 63;
    int kp = blockIdx.x >> 6;
    int tid = threadIdx.x;
    int wv = tid >> 6, lane = tid & 63;
    int quad = lane >> 4, r16 = lane & 15;
    int wm = wv >> 1, wn = wv & 1;
    size_t mbase = (size_t)mblk * 128;
    int kbase = kp * KCHUNK;

    floatx4 acc[4][4];
#pragma unroll
    for (int mi = 0; mi < 4; ++mi)
#pragma unroll
        for (int ni = 0; ni < 4; ++ni) acc[mi][ni] = (floatx4)0.f;

    int srow = lane >> 2;   // 0..15
    int kq = lane & 3;      // 16B chunk within 64B row
    const unsigned short* gA = A + (mbase + wv * 32 + srow) * (size_t)NN + kbase + kq * 8;
    const unsigned short* gB = Bt + (size_t)(wv * 32 + srow) * NN + kbase + kq * 8;
    char* lAw = (char*)lA + wv * 2048;
    char* lBw = (char*)lB + wv * 2048;

    for (int it = 0; it < KCHUNK / 32; ++it) {
        gload16(gA, lAw);
        gload16(gA + (size_t)16 * NN, lAw + 1024);
        gload16(gB, lBw);
        gload16(gB + (size_t)16 * NN, lBw + 1024);
        __syncthreads();   // compiler emits vmcnt(0) drain before barrier
        bf16x8 af[4], bf[4];
#pragma unroll
        for (int mi = 0; mi < 4; ++mi)
            af[mi] = *(const bf16x8*)((const char*)lA + ((wm * 64 + mi * 16 + r16) * 64 + quad * 16));
#pragma unroll
        for (int ni = 0; ni < 4; ++ni)
            bf[ni] = *(const bf16x8*)((const char*)lB + ((wn * 64 + ni * 16 + r16) * 64 + quad * 16));
#pragma unroll
        for (int mi = 0; mi < 4; ++mi)
#pragma unroll
            for (int ni = 0; ni < 4; ++ni)
                acc[mi][ni] = __builtin_amdgcn_mfma_f32_16x16x32_bf16(af[mi], bf[ni], acc[mi][ni], 0, 0, 0);
        __syncthreads();
        gA += 32; gB += 32;
    }

    float* outp = part + (size_t)kp * ((size_t)NN * DH);
#pragma unroll
    for (int mi = 0; mi < 4; ++mi) {
#pragma unroll
        for (int r = 0; r < 4; ++r) {
            size_t i = mbase + wm * 64 + mi * 16 + quad * 4 + r;
            float* op = outp + i * DH + wn * 64 + r16;
#pragma unroll
            for (int ni = 0; ni < 4; ++ni) op[ni * 16] = acc[mi][ni][r];
        }
    }
}

// one block per graph (128 consecutive rows). Sum split-K partials, scale, max, classify.
__global__ __launch_bounds__(256) void k_pool(
    const float* __restrict__ part, const float* __restrict__ rdv,
    const float* __restrict__ wc, const float* __restrict__ bc,
    float* __restrict__ out)
{
    __shared__ float red[256];
    __shared__ float pooled[128];
    int g = blockIdx.x;
    int tid = threadIdx.x;
    int c = tid & 127;
    int half = tid >> 7;
    float mx = -1e30f;
    for (int r = 0; r < 64; ++r) {
        int i = g * 128 + half * 64 + r;
        float s = 0.f;
#pragma unroll
        for (int p = 0; p < SPLITK; ++p)
            s += part[(size_t)p * ((size_t)NN * DH) + (size_t)i * DH + c];
        s *= rsqrtf(rdv[i]);
        mx = fmaxf(mx, s);
    }
    red[tid] = mx;
    __syncthreads();
    if (half == 0) pooled[c] = fmaxf(red[c], red[c + 128]);
    __syncthreads();
    if (tid < NCLS) {
        float a = bc[tid];
        const float* wr = wc + tid * 128;
#pragma unroll 8
        for (int k = 0; k < 128; ++k) a += pooled[k] * wr[k];
        out[g * NCLS + tid] = a;
    }
}

extern "C" void kernel_launch(void* const* d_in, const int* in_sizes, int n_in,
                              void* d_out, int out_size, void* d_ws, size_t ws_size,
                              hipStream_t stream)
{
    const int*   x   = (const int*)  d_in[0];
    const float* m   = (const float*)d_in[1];
    // d_in[2] = bm: graph ids are (i*64)//8192 => 128 consecutive rows per graph (fixed by setup)
    const float* emb = (const float*)d_in[3];
    const float* w1  = (const float*)d_in[4];
    const float* b1  = (const float*)d_in[5];
    const float* w2  = (const float*)d_in[6];
    const float* b2  = (const float*)d_in[7];
    const float* wc  = (const float*)d_in[8];
    const float* bc  = (const float*)d_in[9];
    float* out = (float*)d_out;

    char* ws = (char*)d_ws;
    unsigned short* mb = (unsigned short*)ws;                        // 128 MB bf16 m
    float* rd  = (float*)(ws + (size_t)134217728);                   // 32 KB
    float* cd  = rd + NN;                                            // 32 KB
    unsigned short* msgT = (unsigned short*)(cd + NN);               // 2 MB
    float* part = (float*)((char*)msgT + (size_t)2 * NN * DH);       // 32 MB

    k_zero<<<(2 * NN + 255) / 256, 256, 0, stream>>>(rd, 2 * NN);
    k_deg_cast<<<1024, 256, 0, stream>>>(m, mb, rd, cd);
    k_msg<<<NN / 64, 256, 0, stream>>>(x, emb, nullptr, nullptr, w1, b1, cd, msgT, 1);
    k_gemm<<<64 * SPLITK, 256, 0, stream>>>(mb, msgT, part);
    k_msg<<<NN / 64, 256, 0, stream>>>(nullptr, nullptr, part, rd, w2, b2, cd, msgT, 2);
    k_gemm<<<64 * SPLITK, 256, 0, stream>>>(mb, msgT, part);
    k_pool<<<NGRAPH, 256, 0, stream>>>(part, rd, wc, bc, out);
}